// Round 3
// baseline (185.347 us; speedup 1.0000x reference)
//
#include <hip/hip_runtime.h>
#include <math.h>

#define B 2
#define C 32
#define H 128
#define W 416
#define D 48
#define HW (H*W)
#define CHW (C*HW)
#define EPSN 1e-3f
#define ISCALE 0.05892556509887896f   // 1/sqrt(C*9)
#define LSTR 36                        // LDS column stride (floats): 16B-aligned
#define DSPL (D / 2)                   // disparities per z-block (24)
#define DHALF (DSPL / 2)               // disparities per thread-half (12)
#define WCH 208                        // w-chunk per block
#define NQ 60                          // staged column-quads in k_lr window
#define NCOLA (NQ * 4)                 // 240 staged columns

__device__ __forceinline__ float clip10(float x) {
    return fminf(fmaxf(x, -10.0f), 10.0f);
}

// ---------------------------------------------------------------------------
// k_norm: 3x3 zero-padded box of sql/sqr -> inverse patch norms inl/inr.
__global__ __launch_bounds__(256) void k_norm(const float* __restrict__ sql,
                                              const float* __restrict__ sqr,
                                              float* __restrict__ inl,
                                              float* __restrict__ inr) {
    int idx = blockIdx.x * 256 + threadIdx.x;
    if (idx >= B * HW) return;
    int b = idx / HW, hw = idx - b * HW;
    int h = hw / W, w = hw - h * W;
    float sl = 0.f, sr = 0.f;
#pragma unroll
    for (int di = -1; di <= 1; ++di) {
        int hh = h + di;
        if (hh < 0 || hh >= H) continue;
#pragma unroll
        for (int dj = -1; dj <= 1; ++dj) {
            int ww = w + dj;
            if (ww < 0 || ww >= W) continue;
            int p = b * HW + hh * W + ww;
            sl += sql[p];
            sr += sqr[p];
        }
    }
    inl[idx] = 1.0f / fmaxf(sqrtf(sl), EPSN);
    inr[idx] = 1.0f / fmaxf(sqrtf(sr), EPSN);
}

// ---------------------------------------------------------------------------
// stage_row_v2: stage [C][W] row into LDS transposed [w][c], stride LSTR.
// Used by k_e: its consecutive-v column reads are bank-balanced as-is.
__device__ __forceinline__ void stage_row_v2(const float* __restrict__ gsrc,
                                             float* __restrict__ lds,
                                             int tid, int nthreads) {
    for (int t = tid; t < (W / 4) * C; t += nthreads) {
        int rw = t & 7;
        int cl = (t >> 3) & 7;
        int g  = t >> 6;              // 0..51
        int wg = g % 13;
        int ch = g / 13;              // 0..3
        int c  = ch * 8 + cl;
        int w4 = (wg * 8 + rw) * 4;
        float4 v = *(const float4*)(gsrc + (size_t)c * HW + w4);
        lds[(w4 + 0) * LSTR + c] = v.x;
        lds[(w4 + 1) * LSTR + c] = v.y;
        lds[(w4 + 2) * LSTR + c] = v.z;
        lds[(w4 + 3) * LSTR + c] = v.w;
    }
}

// ---------------------------------------------------------------------------
// stage_win3: stage the VERTICAL 3-tap vsum[c,v] (zero-padded in h and v)
// for the 240-column window [v4, v4+NCOLA) into swizzled LDS:
// channel-group g2 of local column idx lives at slot g2 ^ ((idx>>3)&7).
// The swizzle key (idx>>3)&7 spreads the mod-8 bank-alias classes of both
// stride-1 and stride-2 lane->column maps across all 8 slots.
__device__ __forceinline__ void stage_win3(const float* __restrict__ gsrc,
                                           float* __restrict__ lds,
                                           int h, int v4, int tid, int nthreads) {
    for (int t = tid; t < NQ * C; t += nthreads) {
        int q4 = t % NQ;              // column-quad within window
        int c  = t / NQ;              // 0..31
        int idx0 = 4 * q4;
        int v0 = v4 + idx0;
        int s = (q4 >> 1) & 7;        // (idx>>3)&7, constant over the quad
        int g2 = c >> 2, wd = c & 3;
        float* dst = lds + (size_t)idx0 * LSTR + 4 * (g2 ^ s) + wd;
        float4 val;
        if (v0 >= 0 && v0 + 3 < W) {
            const float* p = gsrc + (size_t)c * HW + v0;
            float4 v = *(const float4*)(p);
            if (h > 0) {
                float4 a = *(const float4*)(p - W);
                v.x += a.x; v.y += a.y; v.z += a.z; v.w += a.w;
            }
            if (h < H - 1) {
                float4 a = *(const float4*)(p + W);
                v.x += a.x; v.y += a.y; v.z += a.z; v.w += a.w;
            }
            val = v;
        } else {
            float e[4];
#pragma unroll
            for (int k = 0; k < 4; ++k) {
                int v = v0 + k;
                float x = 0.f;
                if (v >= 0 && v < W) {
                    const float* p = gsrc + (size_t)c * HW + v;
                    x = p[0];
                    if (h > 0) x += p[-W];
                    if (h < H - 1) x += p[W];
                }
                e[k] = x;
            }
            val = make_float4(e[0], e[1], e[2], e[3]);
        }
        dst[0 * LSTR] = val.x;
        dst[1 * LSTR] = val.y;
        dst[2 * LSTR] = val.z;
        dst[3 * LSTR] = val.w;
    }
}

__device__ __forceinline__ float dot32(const float* __restrict__ fl,
                                       const float* __restrict__ col) {
    const float4* c4 = (const float4*)col;   // 16B-aligned (LSTR*4 = 144)
    float a = 0.0f;
#pragma unroll
    for (int q = 0; q < 8; ++q) {
        float4 v = c4[q];
        a += fl[4 * q + 0] * v.x + fl[4 * q + 1] * v.y
           + fl[4 * q + 2] * v.z + fl[4 * q + 3] * v.w;
    }
    return a;
}

// one swizzled column read -> two dots (w and w+1 fragments).
// s already folds the per-thread fl half-permutation (^ half<<2).
__device__ __forceinline__ void dot32x2s(const float* __restrict__ fl0,
                                         const float* __restrict__ fl1,
                                         const float* __restrict__ col, int s,
                                         float& a0, float& a1) {
    const float4* c4 = (const float4*)col;
    float s0 = 0.f, s1 = 0.f;
#pragma unroll
    for (int q = 0; q < 8; ++q) {
        float4 v = c4[q ^ s];
        s0 += fl0[4 * q + 0] * v.x + fl0[4 * q + 1] * v.y
            + fl0[4 * q + 2] * v.z + fl0[4 * q + 3] * v.w;
        s1 += fl1[4 * q + 0] * v.x + fl1[4 * q + 1] * v.y
            + fl1[4 * q + 2] * v.z + fl1[4 * q + 3] * v.w;
    }
    a0 = s0; a1 = s1;
}

// ---------------------------------------------------------------------------
// k_lr: sL and sR. Grid (H, B, 4): z = zd(0..1 d-split) + 2*wc(0..1 w-chunk).
// Block 256: pairs p own (w,w+1) in the 208-col chunk; half=tid&1 owns 12 d.
// ~35 KB LDS window -> 4 blocks/CU -> 16 waves/CU. fl loads split by half
// (16 channels each) and exchanged via shfl_xor(1); the half-permutation of
// fl order folds into the LDS group swizzle as ^ (half<<2).
__global__ __launch_bounds__(256) void k_lr(const float* __restrict__ xm,
                                            const float* __restrict__ xl,
                                            const float* __restrict__ xr,
                                            const float* __restrict__ inl,
                                            const float* __restrict__ inr,
                                            float* __restrict__ out) {
    __shared__ float sB[NCOLA * LSTR];    // 34560 B
    __shared__ float sIn[NCOLA];          // 960 B
    int tid = threadIdx.x;
    int h = blockIdx.x;
    int b = blockIdx.y;
    int zd = blockIdx.z & 1;
    int wc = blockIdx.z >> 1;
    int d0 = zd * DSPL;
    int w0 = wc * WCH;
    bool act = tid < WCH;             // 208 active
    int p = tid >> 1;                 // pair within chunk
    int half = tid & 1;
    int w = w0 + 2 * p;
    int dbase = d0 + half * DHALF;
    int bhw = b * HW + h * W;
    const float* pm = xm + (size_t)b * CHW + h * W;

    // fl in thread-local channel order: [my 16 channels][partner's 16].
    float fl0[C], fl1[C];
    if (act) {
        float am0 = 0.f, am1 = 0.f;
#pragma unroll
        for (int k = 0; k < 16; ++k) {
            float2 mv = *(const float2*)(pm + (size_t)(16 * half + k) * HW + w);
            fl0[k] = mv.x; fl1[k] = mv.y;
            am0 += mv.x * mv.x; am1 += mv.y * mv.y;
        }
        am0 += __shfl_xor(am0, 1);
        am1 += __shfl_xor(am1, 1);
#pragma unroll
        for (int k = 0; k < 16; ++k) {
            fl0[16 + k] = __shfl_xor(fl0[k], 1);
            fl1[16 + k] = __shfl_xor(fl1[k], 1);
        }
        float im0 = 1.0f / fmaxf(sqrtf(am0), EPSN);
        float im1 = 1.0f / fmaxf(sqrtf(am1), EPSN);
#pragma unroll
        for (int c = 0; c < C; ++c) { fl0[c] *= im0; fl1[c] *= im1; }
    }

    // ---- phase L: columns v = w + dbase - 1 + j. 3-tap completes at center
    // m = v-1 at iter j>=2; store pairs (s0 from j-1, s1 from j) at j>=3 for
    // d = dbase + j - 3.
    int v4L = (w0 + d0 - 1) & ~3;
    stage_win3(xl + (size_t)b * CHW + h * W, sB, h, v4L, tid, 256);
    for (int t = tid; t < NCOLA; t += 256) {
        int v = v4L + t;
        sIn[t] = (v >= 0 && v < W) ? inl[bhw + v] : 0.f;
    }
    __syncthreads();
    if (act) {
        float* o = out + ((size_t)b * 3 + 0) * D * HW + h * W;
        float g0a = 0.f, g0b = 0.f, g1a = 0.f, g1b = 0.f, s0p = 0.f;
#pragma unroll 3
        for (int j = 0; j <= DHALF + 2; ++j) {
            int v = w + dbase - 1 + j;
            float c0 = 0.f, c1 = 0.f;
            if (v >= 0 && v < W) {
                int idx = v - v4L;
                int s = ((idx >> 3) & 7) ^ (half << 2);
                dot32x2s(fl0, fl1, sB + idx * LSTR, s, c0, c1);
            }
            float s0 = 0.f, s1 = 0.f;
            if (j >= 2) {
                int m = v - 1;                 // m >= v4L+1 guaranteed
                if (m < W) {
                    float sc = sIn[m - v4L] * ISCALE;
                    s0 = clip10((g0a + g0b + c0) * sc);
                    s1 = clip10((g1a + g1b + c1) * sc);
                }
                if (j >= 3) {
                    int d = dbase + j - 3;
                    *(float2*)(o + (size_t)d * HW + w) = make_float2(s0p, s1);
                }
            }
            s0p = s0;
            g0a = g0b; g0b = c0;
            g1a = g1b; g1b = c1;
        }
    }
    __syncthreads();

    // ---- phase R: columns v = w - dbase - DHALF + j ascending. Center
    // m = v-1 at iter j>=2; store pairs at j>=3 for d = dbase + DHALF + 2 - j.
    int v4R = (w0 - d0 - DSPL) & ~3;
    stage_win3(xr + (size_t)b * CHW + h * W, sB, h, v4R, tid, 256);
    for (int t = tid; t < NCOLA; t += 256) {
        int v = v4R + t;
        sIn[t] = (v >= 0 && v < W) ? inr[bhw + v] : 0.f;
    }
    __syncthreads();
    if (act) {
        float* o = out + ((size_t)b * 3 + 1) * D * HW + h * W;
        float g0a = 0.f, g0b = 0.f, g1a = 0.f, g1b = 0.f, s0p = 0.f;
#pragma unroll 3
        for (int j = 0; j <= DHALF + 2; ++j) {
            int v = w - dbase - DHALF + j;
            float c0 = 0.f, c1 = 0.f;
            if (v >= 0 && v < W) {
                int idx = v - v4R;
                int s = ((idx >> 3) & 7) ^ (half << 2);
                dot32x2s(fl0, fl1, sB + idx * LSTR, s, c0, c1);
            }
            float s0 = 0.f, s1 = 0.f;
            if (j >= 2) {
                int m = v - 1;                 // m - v4R >= 1 when m >= 0
                if (m >= 0) {
                    float sc = sIn[m - v4R] * ISCALE;
                    s0 = clip10((g0a + g0b + c0) * sc);
                    s1 = clip10((g1a + g1b + c1) * sc);
                }
                if (j >= 3) {
                    int d = dbase + DHALF + 2 - j;
                    *(float2*)(o + (size_t)d * HW + w) = make_float2(s0p, s1);
                }
            }
            s0p = s0;
            g0a = g0b; g0b = c0;
            g1a = g1b; g1b = c1;
        }
    }
}

// ---------------------------------------------------------------------------
// k_e: EH[b,d,h,v] = horizontal 3-tap of E, E[v] = sum_c xl[.,v+2d]*xr[.,v].
// Wave-halo: each wave computes e at v = wave*62 + lane - 1, emits 62 sums
// via shuffles. dc splits d in two -> 2 blocks/CU resident.
// dc==0 blocks additionally emit sql/sqr (channel sum-of-squares rows).
__global__ __launch_bounds__(448) void k_e(const float* __restrict__ xl,
                                           const float* __restrict__ xr,
                                           float* __restrict__ EH,
                                           float* __restrict__ sql,
                                           float* __restrict__ sqr) {
    __shared__ float sXL[W * LSTR];   // 59904 B
    int tid = threadIdx.x;
    int h = blockIdx.x;
    int b = blockIdx.y;
    int d0 = blockIdx.z * DSPL;
    int lane = tid & 63;
    int wv = tid >> 6;                // 0..6
    int v = wv * 62 + lane - 1;       // -1 .. 433
    bool vin = (v >= 0) && (v < W);
    const float* br = xr + (size_t)b * CHW + h * W;

    float xrv[C];
#pragma unroll
    for (int c = 0; c < C; ++c) xrv[c] = vin ? br[c * HW + v] : 0.0f;

    stage_row_v2(xl + (size_t)b * CHW + h * W, sXL, tid, 448);
    __syncthreads();

    bool wr = (lane >= 1) && (lane <= 62) && (v < W);   // v>=0 implied

    if (blockIdx.z == 0) {
        float sr_ = 0.f, sl_ = 0.f;
#pragma unroll
        for (int c = 0; c < C; ++c) sr_ += xrv[c] * xrv[c];
        if (vin) {
            const float4* c4 = (const float4*)(sXL + v * LSTR);
#pragma unroll
            for (int q = 0; q < 8; ++q) {
                float4 x = c4[q];
                sl_ += x.x * x.x + x.y * x.y + x.z * x.z + x.w * x.w;
            }
        }
        if (wr) {
            sqr[b * HW + h * W + v] = sr_;
            sql[b * HW + h * W + v] = sl_;
        }
    }

    float* pe = EH + (((size_t)b * D) * H + h) * W + v;
    for (int d = d0; d < d0 + DSPL; ++d) {
        int s = 2 * d;
        float e = 0.0f;
        if (vin && v + s < W) e = dot32(xrv, sXL + (v + s) * LSTR);
        float em = __shfl_up(e, 1);
        float ep = __shfl_down(e, 1);
        float eh = em + e + ep;
        if (wr) pe[(size_t)d * HW] = eh;
    }
}

// ---------------------------------------------------------------------------
// k_lr2: sLR = vertical 3-tap of EH at column vc=w-d, times inverse norms.
#define DCH 12
__global__ __launch_bounds__(448) void k_lr2(const float* __restrict__ EH,
                                             const float* __restrict__ inl,
                                             const float* __restrict__ inr,
                                             float* __restrict__ out) {
    int w = threadIdx.x;
    int dc = blockIdx.x;              // 0..3
    int h = blockIdx.y;
    int b = blockIdx.z;
    if (w >= W) return;
    int bhw = b * HW + h * W;
    bool hm = (h > 0), hp = (h < H - 1);

    float* o = out + ((size_t)b * 3 + 2) * D * HW + h * W + w;
#pragma unroll
    for (int i = 0; i < DCH; ++i) {
        int d = dc * DCH + i;
        float r = 0.0f;
        if (w >= d && w + d < W) {
            int vc = w - d;
            const float* base = EH + ((size_t)b * D + d) * HW + vc;
            float e = base[h * W];
            if (hm) e += base[(h - 1) * W];
            if (hp) e += base[(h + 1) * W];
            float nl = inl[bhw + w + d];
            float nr = inr[bhw + vc];
            r = clip10(e * nl * nr * ISCALE);
        }
        o[(size_t)d * HW] = r;
    }
}

// ---------------------------------------------------------------------------
extern "C" void kernel_launch(void* const* d_in, const int* in_sizes, int n_in,
                              void* d_out, int out_size, void* d_ws, size_t ws_size,
                              hipStream_t stream) {
    const float* xl = (const float*)d_in[0];
    const float* xm = (const float*)d_in[1];
    const float* xr = (const float*)d_in[2];
    float* out = (float*)d_out;

    float* ws = (float*)d_ws;
    float* inl = ws;                               // B*HW
    float* inr = inl + B * HW;                     // B*HW
    float* sql = inr + B * HW;                     // B*HW
    float* sqr = sql + B * HW;                     // B*HW
    float* EH  = sqr + B * HW;                     // B*D*H*W

    k_e<<<dim3(H, B, 2), dim3(448), 0, stream>>>(xl, xr, EH, sql, sqr);
    k_norm<<<dim3((B * HW + 255) / 256), dim3(256), 0, stream>>>(sql, sqr, inl, inr);
    k_lr<<<dim3(H, B, 4), dim3(256), 0, stream>>>(xm, xl, xr, inl, inr, out);
    k_lr2<<<dim3(4, H, B), dim3(448), 0, stream>>>(EH, inl, inr, out);
}